// Round 18
// baseline (209.454 us; speedup 1.0000x reference)
//
#include <hip/hip_runtime.h>

// StochasticRegionalConvolution — fused MFMA conv, 8x64 tile (page-run x2).
// out[b,co,p,q] = coeff(p,q) * sum_{ci,kh,kw} x[b,ci,p+kh,q+kw] * W[co,ci,kh,kw]
//
// K1: coeff map (256x256 f32)                     -> d_ws[0, 256KB)
// K2: weight transform to MFMA A-frag order, bf16 -> d_ws[256KB, 328KB)
// K3: fused conv: 8x64 pixel tile, 512 thr / 8 waves (4 row-pairs x 2
//     co-halves). ALL staging loads issued upfront (va+vb in regs, R16's
//     batching win); single xs buffer, 4-barrier schedule:
//     write0 | phases0-8 | write1 | phases9-17 | epilogue.
//     Epilogue stores 256 B contiguous per (co,row) — 2x DRAM page run vs
//     the 16/32-q tiles (testing the effective-BW pattern bound).

typedef short short8 __attribute__((ext_vector_type(8)));
typedef float floatx4 __attribute__((ext_vector_type(4)));
typedef unsigned int uint4v __attribute__((ext_vector_type(4)));

#define OUTR 62

__device__ inline unsigned f2bf_pack(float lo, float hi) {
    unsigned ul = __builtin_bit_cast(unsigned, lo);
    unsigned uh = __builtin_bit_cast(unsigned, hi);
    ul = (ul + 0x7FFFu + ((ul >> 16) & 1u)) >> 16;   // RNE
    uh = (uh + 0x7FFFu + ((uh >> 16) & 1u)) >> 16;
    return ul | (uh << 16);
}

__global__ void srconv_coeff_kernel(const int* __restrict__ h_idx,
                                    const int* __restrict__ w_idx,
                                    const float* __restrict__ lam,
                                    int T, float* __restrict__ coeff) {
    int p = blockIdx.x;
    int q = threadIdx.x;
    float c = 0.f;
    for (int t = 0; t < T; ++t) {
        int dh = p - h_idx[t];
        int dw = q - w_idx[t];
        if (dh >= 0 && dh < OUTR && dw >= 0 && dw < OUTR) c += lam[t];
    }
    coeff[(p << 8) + q] = c * (1.0f / 16.0f);
}

__global__ void srconv_wtrans_kernel(const float* __restrict__ wgt,
                                     uint4v* __restrict__ afrag) {
    int id = blockIdx.x * 256 + threadIdx.x;      // [0, 72*64)
    int l  = id & 63;
    int fi = id >> 6;                             // (kk*2+cb)*4 + m
    int m  = fi & 3;
    int cb = (fi >> 2) & 1;
    int kk = fi >> 3;
    int co  = m * 16 + (l & 15);
    int ci0 = cb * 32 + (l >> 4) * 8;
    float w[8];
#pragma unroll
    for (int j = 0; j < 8; ++j)
        w[j] = wgt[(co * 64 + ci0 + j) * 9 + kk];
    uint4v d;
    d.x = f2bf_pack(w[0], w[1]);
    d.y = f2bf_pack(w[2], w[3]);
    d.z = f2bf_pack(w[4], w[5]);
    d.w = f2bf_pack(w[6], w[7]);
    afrag[id] = d;
}

// LDS xs[pix 0..679][16 u32 ci-pairs]; pix = row*68 + col (10 rows x 68 cols).
// slot = cp ^ (((pix>>1)&3)<<2). B-frag (kg): b128 at group kg^((pix>>1)&3).
__launch_bounds__(512, 2)
__global__ void srconv_fused_kernel(const float* __restrict__ x,
                                    const float* __restrict__ coeff,
                                    const short8* __restrict__ afrag,
                                    float* __restrict__ out) {
    __shared__ __align__(16) unsigned xs[680 * 16];   // 43,520 B

    const int tid  = threadIdx.x;
    const int lane = tid & 63;
    const int wv   = tid >> 6;            // 0..7
    const int wvp  = wv & 3;              // row-pair: rows {2wvp, 2wvp+1}
    const int wvc  = wv >> 2;             // co-half (0: co<32, 1: co>=32)
    const int l15  = lane & 15;
    const int kg   = lane >> 4;

    // bijective XCD swizzle: 2048 blocks, 8 XCDs x 256 -> 2 batches per XCD
    const unsigned bid = blockIdx.x;
    const unsigned swz = (bid & 7) * 256 + (bid >> 3);
    const int b    = swz >> 7;            // 16 batches
    const int tile = swz & 127;           // 32 p-tiles x 4 q-tiles
    const int P0   = (tile >> 2) << 3;
    const int Q0   = (tile & 3) << 6;

    // ---- tile skip vote: 512 threads cover the 8x64 coeff tile ----
    float myc = coeff[((P0 + (tid >> 6)) << 8) + Q0 + (tid & 63)];
    if (__syncthreads_count(myc != 0.f) == 0) {
        const floatx4 z = (floatx4){0.f, 0.f, 0.f, 0.f};
        for (int u = tid; u < 64 * 8 * 16; u += 512) {
            int q4 = u & 15;
            int pr = (u >> 4) & 7;
            int co = u >> 7;
            *(floatx4*)(out + (((b << 6) + co) << 16) +
                        ((P0 + pr) << 8) + Q0 + (q4 << 2)) = z;
        }
        return;
    }

    const int prb = P0 + (wvp << 1);

    // ---- hoisted epilogue coeff loads ----
    float cf[2][4];
#pragma unroll
    for (int p = 0; p < 2; ++p)
#pragma unroll
        for (int h = 0; h < 4; ++h)
            cf[p][h] = coeff[((prb + p) << 8) + Q0 + (h << 4) + l15];

    const float* xb = x + ((size_t)b << 22);

    // ---- batched staging (R16 win). Per half: 2720 tasks =
    // 16 cp x 10 rows x 17 chunks (4 cols each, covers cols 0..67).
    floatx4 va[6][2], vb[6][2];

#pragma unroll
    for (int r = 0; r < 6; ++r) {         // ISSUE half 0
        int u  = r * 512 + tid;
        int uc = u < 2720 ? u : 2719;
        int cp    = uc / 170;
        int rem   = uc - cp * 170;
        int row   = rem / 17;
        int chunk = rem - row * 17;
        int gr    = min(P0 + row, 255);
        int gcb   = min(Q0 + (chunk << 2), 252);
        const float* xp = xb + (cp << 17) + (gr << 8) + gcb;
        va[r][0] = *(const floatx4*)(xp);
        va[r][1] = *(const floatx4*)(xp + 65536);
    }

    // areg preload (phases t=0,1: kk0/kk1, cb0); mg selects this wave's co-half
    const int mg = wvc << 1;
    short8 areg[2][2];
#pragma unroll
    for (int m = 0; m < 2; ++m) {
        areg[0][m] = afrag[(0 + mg + m) * 64 + lane];
        areg[1][m] = afrag[(8 + mg + m) * 64 + lane];
    }

#pragma unroll
    for (int r = 0; r < 6; ++r) {         // ISSUE half 1
        int u  = r * 512 + tid;
        int uc = u < 2720 ? u : 2719;
        int cp    = uc / 170;
        int rem   = uc - cp * 170;
        int row   = rem / 17;
        int chunk = rem - row * 17;
        int gr    = min(P0 + row, 255);
        int gcb   = min(Q0 + (chunk << 2), 252);
        const float* xp = xb + ((16 + cp) << 17) + (gr << 8) + gcb;
        vb[r][0] = *(const floatx4*)(xp);
        vb[r][1] = *(const floatx4*)(xp + 65536);
    }

#pragma unroll
    for (int r = 0; r < 6; ++r) {         // WRITE half 0
        int u  = r * 512 + tid;
        int uc = u < 2720 ? u : 2719;
        int cp    = uc / 170;
        int rem   = uc - cp * 170;
        int row   = rem / 17;
        int chunk = rem - row * 17;
#pragma unroll
        for (int j = 0; j < 4; ++j) {
            if (u < 2720) {
                int pix = row * 68 + (chunk << 2) + j;
                int slot = cp ^ (((pix >> 1) & 3) << 2);
                xs[(pix << 4) + slot] = f2bf_pack(va[r][0][j], va[r][1][j]);
            }
        }
    }
    __syncthreads();                      // half-0 ready

    floatx4 acc[2][2][4];                 // [m: co16 in half][p: row][h: q16]
#pragma unroll
    for (int m = 0; m < 2; ++m)
#pragma unroll
        for (int p = 0; p < 2; ++p)
#pragma unroll
            for (int h = 0; h < 4; ++h)
                acc[m][p][h] = (floatx4){0.f, 0.f, 0.f, 0.f};

    // ---- phases 0..8 (ci first half) ----
#pragma unroll
    for (int t = 0; t < 9; ++t) {
        const int kh = t / 3;
        const int kw = t - kh * 3;
        const int cur = t & 1;

        short8 bf[2][4];
#pragma unroll
        for (int p = 0; p < 2; ++p)
#pragma unroll
            for (int h = 0; h < 4; ++h) {
                int prl = (wvp << 1) + p + kh;         // 0..9
                int cl  = (h << 4) + l15 + kw;         // 0..65
                int pix = prl * 68 + cl;
                int off = (pix << 4) +
                          ((kg << 2) ^ (((pix >> 1) & 3) << 2));
                bf[p][h] = *(const short8*)(&xs[off]);
            }
#pragma unroll
        for (int m = 0; m < 2; ++m)
#pragma unroll
            for (int p = 0; p < 2; ++p)
#pragma unroll
                for (int h = 0; h < 4; ++h)
                    acc[m][p][h] = __builtin_amdgcn_mfma_f32_16x16x32_bf16(
                        areg[cur][m], bf[p][h], acc[m][p][h], 0, 0, 0);

        {   // prefetch phase t+2 (cb-aware)
            const int tn  = t + 2;
            const int cbn = tn / 9;
            const int kkn = tn - cbn * 9;
#pragma unroll
            for (int m = 0; m < 2; ++m)
                areg[cur][m] =
                    afrag[((((kkn << 1) + cbn) << 2) + mg + m) * 64 + lane];
        }
    }
    __syncthreads();                      // WAR: all reads of half-0 done

    // ---- WRITE half 1 (vb already resident in registers) ----
#pragma unroll
    for (int r = 0; r < 6; ++r) {
        int u  = r * 512 + tid;
        int uc = u < 2720 ? u : 2719;
        int cp    = uc / 170;
        int rem   = uc - cp * 170;
        int row   = rem / 17;
        int chunk = rem - row * 17;
#pragma unroll
        for (int j = 0; j < 4; ++j) {
            if (u < 2720) {
                int pix = row * 68 + (chunk << 2) + j;
                int slot = cp ^ (((pix >> 1) & 3) << 2);
                xs[(pix << 4) + slot] = f2bf_pack(vb[r][0][j], vb[r][1][j]);
            }
        }
    }
    __syncthreads();                      // half-1 ready

    // ---- phases 9..17 (ci second half) ----
#pragma unroll
    for (int t = 9; t < 18; ++t) {
        const int kk = t - 9;
        const int kh = kk / 3;
        const int kw = kk - kh * 3;
        const int cur = t & 1;

        short8 bf[2][4];
#pragma unroll
        for (int p = 0; p < 2; ++p)
#pragma unroll
            for (int h = 0; h < 4; ++h) {
                int prl = (wvp << 1) + p + kh;
                int cl  = (h << 4) + l15 + kw;
                int pix = prl * 68 + cl;
                int off = (pix << 4) +
                          ((kg << 2) ^ (((pix >> 1) & 3) << 2));
                bf[p][h] = *(const short8*)(&xs[off]);
            }
#pragma unroll
        for (int m = 0; m < 2; ++m)
#pragma unroll
            for (int p = 0; p < 2; ++p)
#pragma unroll
                for (int h = 0; h < 4; ++h)
                    acc[m][p][h] = __builtin_amdgcn_mfma_f32_16x16x32_bf16(
                        areg[cur][m], bf[p][h], acc[m][p][h], 0, 0, 0);

        if (t < 16) {
            const int tn  = t + 2;
            const int kkn = tn - 9;
#pragma unroll
            for (int m = 0; m < 2; ++m)
                areg[cur][m] =
                    afrag[((((kkn << 1) + 1) << 2) + mg + m) * 64 + lane];
        }
    }
    __syncthreads();                      // all waves done reading xs

    // ---- epilogue: per-wave slab [16 co][68 q-pitch] overlaid on xs ----
    // D layout (m89): col = lane&15 -> q16, row = (lane>>4)*4+reg -> co16.
    // Store instr = 4 co-rows x 256 B contiguous each (the page-run x2 win).
    float* epb = reinterpret_cast<float*>(xs) + wv * 1088;   // 8 x 4352 B
    const int co_l = lane >> 4;           // 0..3
    const int q4   = lane & 15;           // 0..15

#pragma unroll
    for (int p = 0; p < 2; ++p) {
        const int pr = prb + p;
#pragma unroll
        for (int m = 0; m < 2; ++m) {
#pragma unroll
            for (int h = 0; h < 4; ++h)
#pragma unroll
                for (int reg = 0; reg < 4; ++reg)
                    epb[((kg << 2) + reg) * 68 + (h << 4) + l15] =
                        acc[m][p][h][reg] * cf[p][h];
            // wave-internal RAW through LDS: compiler-inserted lgkmcnt orders
#pragma unroll
            for (int j = 0; j < 4; ++j) {
                const floatx4 v = *reinterpret_cast<const floatx4*>(
                    &epb[(co_l + (j << 2)) * 68 + (q4 << 2)]);
                const int co = (wvc << 5) + (m << 4) + co_l + (j << 2);
                *(floatx4*)(out + (((b << 6) + co) << 16) +
                            (pr << 8) + Q0 + (q4 << 2)) = v;
            }
        }
    }
}

extern "C" void kernel_launch(void* const* d_in, const int* in_sizes, int n_in,
                              void* d_out, int out_size, void* d_ws, size_t ws_size,
                              hipStream_t stream) {
    const float* x     = (const float*)d_in[0];
    const float* wgt   = (const float*)d_in[1];
    const int*   h_idx = (const int*)d_in[2];
    const int*   w_idx = (const int*)d_in[3];
    const float* lam   = (const float*)d_in[4];
    float*       out   = (float*)d_out;
    float*       coeff = (float*)d_ws;                        // 256 KB
    char*        af_b  = (char*)d_ws + 65536 * sizeof(float); // 72 KB
    const int    T     = in_sizes[2];

    srconv_coeff_kernel<<<256, 256, 0, stream>>>(h_idx, w_idx, lam, T, coeff);
    srconv_wtrans_kernel<<<18, 256, 0, stream>>>(wgt, (uint4v*)af_b);
    // 2048 blocks = (32 p-tiles x 4 q-tiles) x 16 batches, XCD-swizzled
    srconv_fused_kernel<<<2048, 512, 0, stream>>>(
        x, coeff, (const short8*)af_b, out);
}